// Round 1
// baseline (223.359 us; speedup 1.0000x reference)
//
#include <hip/hip_runtime.h>
#include <math.h>

#define NN 2048
#define BATCH 8
#define FDIM 128
#define MASKV -9000000000000000.0f
#define LALPHA 0.2f

// ---------------- kernel 0: zero c and gpre (ws is poisoned each launch) ----
__global__ void k_zero(float* __restrict__ c, float* __restrict__ gpre) {
    int i = blockIdx.x * 256 + threadIdx.x;
    if (i < BATCH * NN) c[i] = 0.f;
    if (i < BATCH * FDIM) gpre[i] = 0.f;
}

// ---------------- kernel 1: positional encoding table pe[2048][128] --------
__global__ void k_pe(float* __restrict__ pe) {
    int i = blockIdx.x * 256 + threadIdx.x;       // 0 .. 2048*128-1
    int n = i >> 7;
    int k = i & 127;
    int jj = k >> 1;
    float dt = expf((float)(2 * jj) * (-0.07195578415606394f)); // -ln(1e4)/128
    float ang = (float)n * dt;
    float decay = 1.f + expf(-(float)n * 0.01f);
    float v = ((k & 1) == 0 ? sinf(ang) : cosf(ang)) * decay;
    pe[i] = v;
}

// ---------------- kernel 2: Wh = (h+pe) @ W ; s1 = Wh@a1 ; s2 = Wh@a2 ------
// block: 256 threads -> 16 col-groups x 16 row-groups; 64 rows x 128 cols tile
// K split into two 64-wide passes so W half (32KB) + hpe tile (17KB) fit LDS.
__global__ __launch_bounds__(256) void k_wh(const float* __restrict__ h,
                                            const float* __restrict__ pe,
                                            const float* __restrict__ W,
                                            const float* __restrict__ a,
                                            float* __restrict__ Wh,
                                            float* __restrict__ s1,
                                            float* __restrict__ s2) {
    __shared__ float w_lds[64 * 128];     // W[kp*64 + k][c]
    __shared__ float hpe_lds[64 * 68];    // rows 64, stride 68 (bank pad)
    const int b  = blockIdx.y;
    const int n0 = blockIdx.x * 64;
    const int t  = threadIdx.x;
    const int tc = t & 15;                // col group -> cols tc*8..+7
    const int tr = t >> 4;                // row group -> rows tr*4..+3

    float acc[4][8];
#pragma unroll
    for (int i = 0; i < 4; i++)
#pragma unroll
        for (int j = 0; j < 8; j++) acc[i][j] = 0.f;

    for (int kp = 0; kp < 2; ++kp) {
        // load W half: 8192 floats
        {
            const float4* wsrc = (const float4*)(W + kp * 64 * 128);
            float4* wdst = (float4*)w_lds;
#pragma unroll
            for (int q = 0; q < 8; q++) wdst[t + q * 256] = wsrc[t + q * 256];
        }
        // load hpe tile: rows n0..n0+63, k in [kp*64, kp*64+64)
        {
#pragma unroll
            for (int q = 0; q < 4; q++) {
                int f = t + q * 256;          // float4 index 0..1023
                int r = f >> 4;               // row 0..63
                int k4 = (f & 15) << 2;       // k offset 0..60
                int n = n0 + r;
                int kk = kp * 64 + k4;
                const float* hp_src = h + ((size_t)b * NN + n) * FDIM + kk;
                float4 hv = *(const float4*)hp_src;
                float4 pv = *(const float4*)(pe + (size_t)n * FDIM + kk);
                float4 hpv = make_float4(hv.x + pv.x, hv.y + pv.y,
                                         hv.z + pv.z, hv.w + pv.w);
                *(float4*)(hpe_lds + r * 68 + k4) = hpv;
            }
        }
        __syncthreads();
#pragma unroll 4
        for (int k = 0; k < 64; k++) {
            float wv[8];
            float4 wa = *(float4*)(w_lds + k * 128 + tc * 8);
            float4 wb = *(float4*)(w_lds + k * 128 + tc * 8 + 4);
            wv[0] = wa.x; wv[1] = wa.y; wv[2] = wa.z; wv[3] = wa.w;
            wv[4] = wb.x; wv[5] = wb.y; wv[6] = wb.z; wv[7] = wb.w;
#pragma unroll
            for (int i = 0; i < 4; i++) {
                float hv = hpe_lds[(tr * 4 + i) * 68 + k];
#pragma unroll
                for (int j = 0; j < 8; j++) acc[i][j] = fmaf(hv, wv[j], acc[i][j]);
            }
        }
        __syncthreads();
    }

    // epilogue: write Wh, reduce s1/s2 across the 16 col-groups (consecutive lanes)
    float a1v[8], a2v[8];
#pragma unroll
    for (int j = 0; j < 8; j++) { a1v[j] = a[tc * 8 + j]; a2v[j] = a[FDIM + tc * 8 + j]; }
#pragma unroll
    for (int i = 0; i < 4; i++) {
        int n = n0 + tr * 4 + i;
        float* dst = Wh + ((size_t)b * NN + n) * FDIM + tc * 8;
        *(float4*)dst = make_float4(acc[i][0], acc[i][1], acc[i][2], acc[i][3]);
        *(float4*)(dst + 4) = make_float4(acc[i][4], acc[i][5], acc[i][6], acc[i][7]);
        float p1 = 0.f, p2 = 0.f;
#pragma unroll
        for (int j = 0; j < 8; j++) {
            p1 = fmaf(acc[i][j], a1v[j], p1);
            p2 = fmaf(acc[i][j], a2v[j], p2);
        }
#pragma unroll
        for (int off = 1; off < 16; off <<= 1) {
            p1 += __shfl_xor(p1, off, 64);
            p2 += __shfl_xor(p2, off, 64);
        }
        if (tc == 0) {
            s1[(size_t)b * NN + n] = p1;
            s2[(size_t)b * NN + n] = p2;
        }
    }
}

// ---------------- kernel 3: stream adj, row softmax, column-sum into c -----
// grid (64 chunks, 8 b), 256 threads = 4 independent waves.
// wave handles rows r = wave, wave+4, ... (8 rows); lane holds 32 m-values.
__global__ __launch_bounds__(256) void k_attn(const float* __restrict__ adj,
                                              const float* __restrict__ s1,
                                              const float* __restrict__ s2,
                                              float* __restrict__ c) {
    const int b = blockIdx.y;
    const int chunk = blockIdx.x;      // 32 rows per chunk
    const int t = threadIdx.x;
    const int wave = t >> 6;
    const int lane = t & 63;
    __shared__ float c_lds[NN];        // 8KB
    for (int i = t; i < NN; i += 256) c_lds[i] = 0.f;

    const float* s2b = s2 + (size_t)b * NN;
    float s2v[32];
#pragma unroll
    for (int kq = 0; kq < 8; kq++) {
        float4 v = *(const float4*)(s2b + kq * 256 + lane * 4);
        s2v[kq * 4 + 0] = v.x; s2v[kq * 4 + 1] = v.y;
        s2v[kq * 4 + 2] = v.z; s2v[kq * 4 + 3] = v.w;
    }
    float c_acc[32];
#pragma unroll
    for (int j = 0; j < 32; j++) c_acc[j] = 0.f;

    const int nbase = chunk * 32;
    const float* adjb = adj + (size_t)b * NN * NN;
    const float* s1b = s1 + (size_t)b * NN;

    for (int r = wave; r < 32; r += 4) {
        int n = nbase + r;
        if (n == 0) continue;          // valid[:,0] = False -> row 0 never used
        float s1n = s1b[n];
        const float* arow = adjb + (size_t)n * NN;
        float val[32];
        float vmax = MASKV;
#pragma unroll
        for (int kq = 0; kq < 8; kq++) {
            float4 av = *(const float4*)(arow + kq * 256 + lane * 4);
            float a4[4] = {av.x, av.y, av.z, av.w};
#pragma unroll
            for (int e = 0; e < 4; e++) {
                int m = kq * 256 + lane * 4 + e;
                float ev = s1n + s2v[kq * 4 + e];
                ev = (ev >= 0.f) ? ev : LALPHA * ev;
                bool conn = (a4[e] > 0.f) || (m == n);   // forced diagonal
                float v = conn ? ev : MASKV;
                val[kq * 4 + e] = v;
                vmax = fmaxf(vmax, v);
            }
        }
#pragma unroll
        for (int off = 32; off; off >>= 1) vmax = fmaxf(vmax, __shfl_xor(vmax, off, 64));
        float zsum = 0.f;
#pragma unroll
        for (int j = 0; j < 32; j++) {
            float p = __expf(val[j] - vmax);   // masked -> exp(-9e15) == 0
            val[j] = p;
            zsum += p;
        }
#pragma unroll
        for (int off = 32; off; off >>= 1) zsum += __shfl_xor(zsum, off, 64);
        float rz = 1.f / zsum;
#pragma unroll
        for (int j = 0; j < 32; j++) c_acc[j] = fmaf(val[j], rz, c_acc[j]);
    }

    __syncthreads();                    // zeroing + all waves done
    for (int w = 0; w < 4; w++) {       // sequential wave combine (no LDS atomics)
        if (wave == w) {
#pragma unroll
            for (int kq = 0; kq < 8; kq++)
#pragma unroll
                for (int e = 0; e < 4; e++)
                    c_lds[kq * 256 + lane * 4 + e] += c_acc[kq * 4 + e];
        }
        __syncthreads();
    }
    for (int i = t; i < NN; i += 256)
        atomicAdd(&c[(size_t)b * NN + i], c_lds[i]);
}

// ---------------- kernel 4: gpre[b][o] = sum_m c[b][m]*Wh[b][m][o] ---------
// grid (32 m-chunks of 64, 8 b), 256 threads = 2 m-halves x 128 o
__global__ __launch_bounds__(256) void k_gpre(const float* __restrict__ Wh,
                                              const float* __restrict__ c,
                                              float* __restrict__ gpre) {
    const int b = blockIdx.y;
    const int m0 = blockIdx.x * 64;
    const int t = threadIdx.x;
    const int o = t & 127;
    const int mh = t >> 7;              // 0/1
    __shared__ float c_lds[64];
    if (t < 64) c_lds[t] = c[(size_t)b * NN + m0 + t];
    __syncthreads();
    float acc = 0.f;
    const float* whb = Wh + ((size_t)b * NN + m0 + mh * 32) * FDIM;
#pragma unroll 4
    for (int mm = 0; mm < 32; mm++)
        acc = fmaf(c_lds[mh * 32 + mm], whb[mm * FDIM + o], acc);
    atomicAdd(&gpre[b * FDIM + o], acc);
}

// ---------------- kernel 5: out = elu(gpre / 2047) -------------------------
__global__ void k_elu(const float* __restrict__ gpre, float* __restrict__ out) {
    int i = blockIdx.x * 256 + threadIdx.x;
    if (i < BATCH * FDIM) {
        float g = gpre[i] * (1.0f / 2047.0f);
        out[i] = g > 0.f ? g : expm1f(g);
    }
}

extern "C" void kernel_launch(void* const* d_in, const int* in_sizes, int n_in,
                              void* d_out, int out_size, void* d_ws, size_t ws_size,
                              hipStream_t stream) {
    (void)in_sizes; (void)n_in; (void)out_size; (void)ws_size;
    const float* h   = (const float*)d_in[0];
    const float* adj = (const float*)d_in[1];
    const float* W   = (const float*)d_in[2];
    const float* a   = (const float*)d_in[3];
    float* out = (float*)d_out;

    char* ws = (char*)d_ws;
    float* Wh   = (float*)ws;                                   // 8*2048*128
    float* pe   = (float*)(ws + (size_t)BATCH * NN * FDIM * 4); // 2048*128
    float* s1   = pe + (size_t)NN * FDIM;                       // 8*2048
    float* s2   = s1 + (size_t)BATCH * NN;
    float* c    = s2 + (size_t)BATCH * NN;
    float* gpre = c + (size_t)BATCH * NN;                       // 8*128

    hipLaunchKernelGGL(k_zero, dim3(64), dim3(256), 0, stream, c, gpre);
    hipLaunchKernelGGL(k_pe, dim3(NN * FDIM / 256), dim3(256), 0, stream, pe);
    hipLaunchKernelGGL(k_wh, dim3(NN / 64, BATCH), dim3(256), 0, stream,
                       h, pe, W, a, Wh, s1, s2);
    hipLaunchKernelGGL(k_attn, dim3(NN / 32, BATCH), dim3(256), 0, stream,
                       adj, s1, s2, c);
    hipLaunchKernelGGL(k_gpre, dim3(NN / 64, BATCH), dim3(256), 0, stream,
                       Wh, c, gpre);
    hipLaunchKernelGGL(k_elu, dim3(4), dim3(256), 0, stream, gpre, out);
}